// Round 5
// baseline (450.180 us; speedup 1.0000x reference)
//
#include <hip/hip_runtime.h>

// FireLSTM: x[8192,512,4] fp32 -> LSTM(H=64) -> FC(64->1), out[8192] fp32.
//
// 1024 blocks x 256 thr (4 waves), block owns 8 batch rows -> 4 blocks/CU
// (4 waves/SIMD; R4 was grid-limited at 2). Wave wv owns h-cols [16wv,16wv+16)
// for ALL 4 gate types: 12x mfma_f32_16x16x32_f16 per step (4 types x K=96).
// D rows = batch: only rows 0..7 valid (rows 8..15 read permanently-zero LDS
// and are discarded). Cells are redistributed across the whole wave with
// __shfl_xor(..,32) (lane i <-> i^32) so all 64 lanes do 2 cells each ->
// trans wave-insts halve vs the naive half-masked layout.
// Bias enters the MFMA via K-slots 68/69 (A=1.0, B=bias as fp16 hi+lo), with
// a persistent zero C operand -> no per-step acc init movs. ax is built
// unconditionally: B k-rows 72..95 are zero, so dead-lane garbage cancels.
// h double-buffered fp16 XOR-swizzled LDS, 1 barrier/step. Weights pre-scaled
// by log2e (2*log2e for g): 8 trans/cell (5 exp2 + 3 rcp), fully reg-local.

typedef float f32x4 __attribute__((ext_vector_type(4)));
typedef _Float16 f16x8 __attribute__((ext_vector_type(8)));
typedef _Float16 f16x4 __attribute__((ext_vector_type(4)));

#define TSEQ 512
#define IDIM 4
#define BPB 8
#define TCH 32              // x staging chunk, in steps
#define L2E 1.44269504088896340736f

#if __has_builtin(__builtin_amdgcn_exp2f)
#define EX2(v) __builtin_amdgcn_exp2f(v)
#else
#define EX2(v) exp2f(v)
#endif
#define RCP(v) __builtin_amdgcn_rcpf(v)

__global__ __launch_bounds__(256, 4) void lstm_fused(
    const float* __restrict__ x,
    const float* __restrict__ W_ih,
    const float* __restrict__ W_hh,
    const float* __restrict__ b_ih,
    const float* __restrict__ b_hh,
    const float* __restrict__ W_fc,
    const float* __restrict__ b_fc,
    float* __restrict__ out)
{
    __shared__ __align__(16) _Float16 hbuf[2][16 * 64];   // 4 KB; rows 8-15 stay 0
    __shared__ __align__(8)  f16x4    xstage[16 * 33];    // 4224 B; rows 8-15 stay 0

    const int tid  = threadIdx.x;
    const int lane = tid & 63;
    const int wv   = tid >> 6;       // wave id == h-column group
    const int b0   = blockIdx.x * BPB;
    const int r    = lane & 15;      // D col (h within group) / A row (batch)
    const int g16  = lane >> 4;      // k-group

    // ---- B-fragments: 4 gate types x K=96, pre-scaled by log2e, registers ----
    // k map: k = ks*32 + 8*g16 + j. Third frag (ks=2): k=64..67 -> W_ih,
    // k=68,69 -> bias (hi,lo) against A=1.0, k>=70 -> 0.
    f16x8 bfrag[4][3];
    #pragma unroll
    for (int t4 = 0; t4 < 4; ++t4) {
        const float sc = (t4 == 2) ? 2.0f * L2E : L2E;   // g-gate gets tanh's 2x
        const int g = t4 * 64 + wv * 16 + r;             // gate row (type t4, col r)
        #pragma unroll
        for (int ks = 0; ks < 2; ++ks) {                 // k 0..63: W_hh
            const float* p = W_hh + g * 64 + ks * 32 + g16 * 8;
            f16x8 f;
            #pragma unroll
            for (int j = 0; j < 8; ++j) f[j] = (_Float16)(p[j] * sc);
            bfrag[t4][ks] = f;
        }
        f16x8 f;
        #pragma unroll
        for (int j = 0; j < 8; ++j) f[j] = (_Float16)0.0f;
        if (g16 == 0) {
            #pragma unroll
            for (int j = 0; j < 4; ++j) f[j] = (_Float16)(W_ih[g * IDIM + j] * sc);
            float biasf = (b_ih[g] + b_hh[g]) * sc;
            _Float16 hi = (_Float16)biasf;
            f[4] = hi;
            f[5] = (_Float16)(biasf - (float)hi);
        }
        bfrag[t4][2] = f;
    }
    const float wfc = W_fc[lane];
    const float bfc = b_fc[0];
    const f32x4 zero4 = {0.f, 0.f, 0.f, 0.f};            // persistent C operand

    float c_reg[2] = {0.f, 0.f};
    for (int i = tid; i < 2 * 16 * 64; i += 256) ((_Float16*)hbuf)[i] = (_Float16)0.0f;
    {
        f16x4 z; z[0] = z[1] = z[2] = z[3] = (_Float16)0.0f;
        for (int i = tid; i < 16 * 33; i += 256) xstage[i] = z;
    }

    // ---- x chunk-0 prefetch: 8 rows x 32 steps, one float4/thread ----
    const int bb = tid >> 5, tf = tid & 31;
    const float* xg = x + ((size_t)(b0 + bb) * TSEQ + tf) * IDIM;
    float4 xn = *(const float4*)xg;

    // ---- precomputed LDS byte offsets ----
    const int hbase = r * 128;                            // A-read row (batch=r)
    const int hs0 = ((g16 + 0) << 4) ^ ((r & 7) << 4);    // k 0..31 chunk
    const int hs1 = ((g16 + 4) << 4) ^ ((r & 7) << 4);    // k 32..63 chunk
    // cell ownership after redistribution: g16=0->bat{0,1}, 1->{4,5}, 2->{2,3}, 3->{6,7}
    const int bat0 = ((g16 & 1) << 2) | ((g16 >> 1) << 1);
    int hwb[2];
    #pragma unroll
    for (int q = 0; q < 2; ++q) {
        const int bat = bat0 + q;
        hwb[q] = (bat * 128 + (wv * 16 + r) * 2) ^ ((bat & 7) << 4);
    }
    const bool lowhalf = (lane < 32);
    char* hb0 = (char*)&hbuf[0][0];
    char* hb1 = (char*)&hbuf[1][0];

    auto step = [&](int tt, const char* rb, char* wb) {
        f16x8 a0 = *(const f16x8*)(rb + hbase + hs0);
        f16x8 a1 = *(const f16x8*)(rb + hbase + hs1);
        f16x4 xv = xstage[r * 33 + tt];
        f16x8 ax;
        ax[0] = xv[0]; ax[1] = xv[1]; ax[2] = xv[2]; ax[3] = xv[3];
        ax[4] = (_Float16)1.0f; ax[5] = (_Float16)1.0f;   // bias slots (k=68,69)
        ax[6] = (_Float16)0.0f; ax[7] = (_Float16)0.0f;

        f32x4 acc[4];
        __builtin_amdgcn_s_setprio(1);
        #pragma unroll
        for (int t4 = 0; t4 < 4; ++t4) {
            f32x4 a;
            a = __builtin_amdgcn_mfma_f32_16x16x32_f16(a0, bfrag[t4][0], zero4, 0, 0, 0);
            a = __builtin_amdgcn_mfma_f32_16x16x32_f16(a1, bfrag[t4][1], a, 0, 0, 0);
            a = __builtin_amdgcn_mfma_f32_16x16x32_f16(ax, bfrag[t4][2], a, 0, 0, 0);
            acc[t4] = a;
        }
        __builtin_amdgcn_s_setprio(0);

        // redistribute: lower lanes keep q=0,1; upper lanes take partner's q=2,3
        float v[4][2];
        #pragma unroll
        for (int t4 = 0; t4 < 4; ++t4) {
            float u2 = __shfl_xor(acc[t4][2], 32);
            float u3 = __shfl_xor(acc[t4][3], 32);
            v[t4][0] = lowhalf ? acc[t4][0] : u2;
            v[t4][1] = lowhalf ? acc[t4][1] : u3;
        }

        // register-local combined activations: 8 trans/cell (5 exp2 + 3 rcp)
        #pragma unroll
        for (int q = 0; q < 2; ++q) {
            float ei = EX2(-v[0][q]);                    // e^-ai
            float ef = EX2(-v[1][q]);
            float eg = EX2(-v[2][q]);                    // e^-2ag
            float eo = EX2(-v[3][q]);
            float ig = (1.f - eg) * RCP((1.f + ei) * (1.f + eg));  // i*g
            float ff = RCP(1.f + ef);                              // f
            float c  = ff * c_reg[q] + ig;
            c_reg[q] = c;
            float uc = fminf(fmaxf(c * (2.0f * L2E), -60.f), 60.f);
            float et = EX2(-uc);                                   // e^-2c
            float h  = (1.f - et) * RCP((1.f + eo) * (1.f + et));  // o*tanh(c)
            *(_Float16*)(wb + hwb[q]) = (_Float16)h;
        }
        __syncthreads();   // h_t visible; next step flips parity
    };

    for (int tc = 0; tc < TSEQ; tc += TCH) {
        // stage x chunk (fp32 reg -> fp16 LDS), then issue next chunk's load
        f16x4 s;
        s[0] = (_Float16)xn.x; s[1] = (_Float16)xn.y;
        s[2] = (_Float16)xn.z; s[3] = (_Float16)xn.w;
        xstage[bb * 33 + tf] = s;
        __syncthreads();
        if (tc + TCH < TSEQ) xn = *(const float4*)(xg + (tc + TCH) * IDIM);

        #pragma unroll 2
        for (int tt = 0; tt < TCH; tt += 2) {   // parity unrolled
            step(tt,     hb0, hb1);
            step(tt + 1, hb1, hb0);
        }
    }

    // ---- FC epilogue: final h is in hbuf[0] (t=511 wrote parity 0) ----
    #pragma unroll
    for (int q = 0; q < 2; ++q) {
        const int bat = wv * 2 + q;
        const int byte = (bat * 128 + lane * 2) ^ ((bat & 7) << 4);
        float hv = (float)*(const _Float16*)(hb0 + byte);
        float partial = hv * wfc;
        #pragma unroll
        for (int off = 32; off > 0; off >>= 1)
            partial += __shfl_down(partial, off);
        if (lane == 0) out[b0 + bat] = partial + bfc;
    }
}

extern "C" void kernel_launch(void* const* d_in, const int* in_sizes, int n_in,
                              void* d_out, int out_size, void* d_ws, size_t ws_size,
                              hipStream_t stream) {
    const float* x    = (const float*)d_in[0];
    const float* W_ih = (const float*)d_in[1];
    const float* W_hh = (const float*)d_in[2];
    const float* b_ih = (const float*)d_in[3];
    const float* b_hh = (const float*)d_in[4];
    const float* W_fc = (const float*)d_in[5];
    const float* b_fc = (const float*)d_in[6];
    float* out = (float*)d_out;

    const int B = in_sizes[0] / (TSEQ * IDIM);   // 8192
    lstm_fused<<<B / BPB, 256, 0, stream>>>(x, W_ih, W_hh, b_ih, b_hh, W_fc, b_fc, out);
}

// Round 6
// 412.067 us; speedup vs baseline: 1.0925x; 1.0925x over previous
//
#include <hip/hip_runtime.h>

// FireLSTM: x[8192,512,4] fp32 -> LSTM(H=64) -> FC(64->1), out[8192] fp32.
//
// 256 blocks x 256 thr (4 waves) = 1 block/CU, 1 wave/SIMD. Block owns 32
// batch rows as TWO INDEPENDENT groups of 16 (independent recurrences).
// Wave wv owns h-cols [16wv,16wv+16) for all 4 gate types, for BOTH groups:
// per step 2 x 12 mfma_f32_16x16x32_f16 (full 16-row M tiles, no waste).
// The two groups are interleaved in program order so G1's ds_read+MFMA issue
// hides under G0's activation chain and vice versa (explicit ILP instead of
// relying on 2 co-resident waves to stagger -- R4/R5 showed they phase-lock).
// Bias enters via K-slots 68/69 (A=1.0, B=bias hi+lo fp16), C operand is a
// persistent zero reg -> no per-step acc-init movs. ax built unconditionally
// (B k-rows 72..95 are zero). h double-buffered fp16 XOR-swizzled LDS,
// ONE barrier/step for both groups. Weights pre-scaled by log2e (2*log2e for
// g-gate): 8 trans/cell (5 exp2 + 3 rcp), activations fully register-local.

typedef float f32x4 __attribute__((ext_vector_type(4)));
typedef _Float16 f16x8 __attribute__((ext_vector_type(8)));
typedef _Float16 f16x4 __attribute__((ext_vector_type(4)));

#define TSEQ 512
#define IDIM 4
#define BPB 32              // 2 groups x 16
#define TCH 32              // x staging chunk, in steps
#define L2E 1.44269504088896340736f

#if __has_builtin(__builtin_amdgcn_exp2f)
#define EX2(v) __builtin_amdgcn_exp2f(v)
#else
#define EX2(v) exp2f(v)
#endif
#define RCP(v) __builtin_amdgcn_rcpf(v)

__global__ __launch_bounds__(256, 1) void lstm_fused(
    const float* __restrict__ x,
    const float* __restrict__ W_ih,
    const float* __restrict__ W_hh,
    const float* __restrict__ b_ih,
    const float* __restrict__ b_hh,
    const float* __restrict__ W_fc,
    const float* __restrict__ b_fc,
    float* __restrict__ out)
{
    __shared__ __align__(16) _Float16 hbuf[2][2][16 * 64];  // [parity][group], 8 KB
    __shared__ __align__(8)  f16x4    xstage[2][16][33];    // [group][row][step], 8448 B

    const int tid  = threadIdx.x;
    const int lane = tid & 63;
    const int wv   = tid >> 6;       // wave id == h-column group
    const int b0   = blockIdx.x * BPB;
    const int r    = lane & 15;      // D col (h within group) / A row (batch)
    const int g16  = lane >> 4;      // k-group

    // ---- B-fragments (shared by both groups): 4 types x K=96, pre-scaled ----
    // k = ks*32 + 8*g16 + j. ks=2 frag: k=64..67 -> W_ih, k=68,69 -> bias
    // (hi,lo fp16) against A=1.0, k>=70 -> 0.
    f16x8 bfrag[4][3];
    #pragma unroll
    for (int t4 = 0; t4 < 4; ++t4) {
        const float sc = (t4 == 2) ? 2.0f * L2E : L2E;   // g-gate gets tanh's 2x
        const int g = t4 * 64 + wv * 16 + r;
        #pragma unroll
        for (int ks = 0; ks < 2; ++ks) {                 // k 0..63: W_hh
            const float* p = W_hh + g * 64 + ks * 32 + g16 * 8;
            f16x8 f;
            #pragma unroll
            for (int j = 0; j < 8; ++j) f[j] = (_Float16)(p[j] * sc);
            bfrag[t4][ks] = f;
        }
        f16x8 f;
        #pragma unroll
        for (int j = 0; j < 8; ++j) f[j] = (_Float16)0.0f;
        if (g16 == 0) {
            #pragma unroll
            for (int j = 0; j < 4; ++j) f[j] = (_Float16)(W_ih[g * IDIM + j] * sc);
            float biasf = (b_ih[g] + b_hh[g]) * sc;
            _Float16 hi = (_Float16)biasf;
            f[4] = hi;
            f[5] = (_Float16)(biasf - (float)hi);
        }
        bfrag[t4][2] = f;
    }
    const float wfc = W_fc[lane];
    const float bfc = b_fc[0];
    const f32x4 zero4 = {0.f, 0.f, 0.f, 0.f};            // persistent C operand

    float c0[4] = {0.f, 0.f, 0.f, 0.f};                  // group 0 cell state
    float c1[4] = {0.f, 0.f, 0.f, 0.f};                  // group 1 cell state
    for (int i = tid; i < 2 * 16 * 64; i += 256)         // zero parity-0, both groups
        ((_Float16*)&hbuf[0][0][0])[i] = (_Float16)0.0f;

    // ---- x chunk-0 prefetch: 32 rows x 32 steps, 4 float4/thread ----
    const int row  = tid >> 3;           // 0..31 (block-local batch)
    const int grp  = row >> 4, lrow = row & 15;
    const int st0  = (tid & 7) * 4;      // 4 consecutive steps
    const float* xg = x + ((size_t)(b0 + row) * TSEQ + st0) * IDIM;
    float4 xp[4];
    #pragma unroll
    for (int j = 0; j < 4; ++j) xp[j] = *(const float4*)(xg + j * IDIM);

    // ---- precomputed LDS byte offsets ----
    const int hbase = r * 128;
    const int hs0 = ((g16 + 0) << 4) ^ ((r & 7) << 4);
    const int hs1 = ((g16 + 4) << 4) ^ ((r & 7) << 4);
    int hw[4];
    #pragma unroll
    for (int q = 0; q < 4; ++q) {
        const int bat = 4 * g16 + q;                     // D row = batch (local)
        hw[q] = (bat * 128 + (wv * 16 + r) * 2) ^ ((bat & 7) << 4);
    }
    char* hb[2][2];
    #pragma unroll
    for (int p = 0; p < 2; ++p)
        #pragma unroll
        for (int g = 0; g < 2; ++g) hb[p][g] = (char*)&hbuf[p][g][0];

    // combined activation + state update for one group's 4 cells
    auto upd = [&](const f32x4* acc, float* cr, char* wb) {
        #pragma unroll
        for (int q = 0; q < 4; ++q) {
            float ei = EX2(-acc[0][q]);                    // e^-ai
            float ef = EX2(-acc[1][q]);
            float eg = EX2(-acc[2][q]);                    // e^-2ag
            float eo = EX2(-acc[3][q]);
            float ig = (1.f - eg) * RCP((1.f + ei) * (1.f + eg));  // i*g
            float ff = RCP(1.f + ef);                              // f
            float c  = ff * cr[q] + ig;
            cr[q] = c;
            float uc = fminf(fmaxf(c * (2.0f * L2E), -60.f), 60.f);
            float et = EX2(-uc);                                   // e^-2c
            float h  = (1.f - et) * RCP((1.f + eo) * (1.f + et));  // o*tanh(c)
            *(_Float16*)(wb + hw[q]) = (_Float16)h;
        }
    };

    auto mfma12 = [&](f16x8 a0, f16x8 a1, f16x8 ax, f32x4* acc) {
        __builtin_amdgcn_s_setprio(1);
        #pragma unroll
        for (int t4 = 0; t4 < 4; ++t4) {
            f32x4 a;
            a = __builtin_amdgcn_mfma_f32_16x16x32_f16(a0, bfrag[t4][0], zero4, 0, 0, 0);
            a = __builtin_amdgcn_mfma_f32_16x16x32_f16(a1, bfrag[t4][1], a, 0, 0, 0);
            a = __builtin_amdgcn_mfma_f32_16x16x32_f16(ax, bfrag[t4][2], a, 0, 0, 0);
            acc[t4] = a;
        }
        __builtin_amdgcn_s_setprio(0);
    };

    auto step = [&](int tt, const char* rb0, const char* rb1, char* wb0, char* wb1) {
        // G0: load + MFMA
        f16x8 a00 = *(const f16x8*)(rb0 + hbase + hs0);
        f16x8 a01 = *(const f16x8*)(rb0 + hbase + hs1);
        f16x4 xv0 = xstage[0][r][tt];
        f16x8 ax0;
        ax0[0] = xv0[0]; ax0[1] = xv0[1]; ax0[2] = xv0[2]; ax0[3] = xv0[3];
        ax0[4] = (_Float16)1.0f; ax0[5] = (_Float16)1.0f;
        ax0[6] = (_Float16)0.0f; ax0[7] = (_Float16)0.0f;
        f32x4 acc0[4];
        mfma12(a00, a01, ax0, acc0);

        // G1: load + MFMA (independent -> overlaps G0's MFMA/trans latency)
        f16x8 a10 = *(const f16x8*)(rb1 + hbase + hs0);
        f16x8 a11 = *(const f16x8*)(rb1 + hbase + hs1);
        f16x4 xv1 = xstage[1][r][tt];
        f16x8 ax1;
        ax1[0] = xv1[0]; ax1[1] = xv1[1]; ax1[2] = xv1[2]; ax1[3] = xv1[3];
        ax1[4] = (_Float16)1.0f; ax1[5] = (_Float16)1.0f;
        ax1[6] = (_Float16)0.0f; ax1[7] = (_Float16)0.0f;
        f32x4 acc1[4];
        mfma12(a10, a11, ax1, acc1);

        // trans chains (each hides the other group's MFMA execution)
        upd(acc0, c0, wb0);
        upd(acc1, c1, wb1);
        __syncthreads();   // h_t visible for both groups; next step flips parity
    };

    for (int tc = 0; tc < TSEQ; tc += TCH) {
        // stage x chunk (fp32 regs -> fp16 LDS), then issue next chunk's loads
        #pragma unroll
        for (int j = 0; j < 4; ++j) {
            f16x4 s;
            s[0] = (_Float16)xp[j].x; s[1] = (_Float16)xp[j].y;
            s[2] = (_Float16)xp[j].z; s[3] = (_Float16)xp[j].w;
            xstage[grp][lrow][st0 + j] = s;
        }
        __syncthreads();
        if (tc + TCH < TSEQ) {
            #pragma unroll
            for (int j = 0; j < 4; ++j)
                xp[j] = *(const float4*)(xg + ((tc + TCH) + j) * IDIM);
        }
        for (int tt = 0; tt < TCH; tt += 2) {   // parity unrolled
            step(tt,     hb[0][0], hb[0][1], hb[1][0], hb[1][1]);
            step(tt + 1, hb[1][0], hb[1][1], hb[0][0], hb[0][1]);
        }
    }

    // ---- FC epilogue: final h in parity 0 (both groups) ----
    #pragma unroll
    for (int g = 0; g < 2; ++g) {
        #pragma unroll
        for (int q = 0; q < 4; ++q) {
            const int bat = wv * 4 + q;
            const int byte = (bat * 128 + lane * 2) ^ ((bat & 7) << 4);
            float hv = (float)*(const _Float16*)(hb[0][g] + byte);
            float partial = hv * wfc;
            #pragma unroll
            for (int off = 32; off > 0; off >>= 1)
                partial += __shfl_down(partial, off);
            if (lane == 0) out[b0 + g * 16 + bat] = partial + bfc;
        }
    }
}

extern "C" void kernel_launch(void* const* d_in, const int* in_sizes, int n_in,
                              void* d_out, int out_size, void* d_ws, size_t ws_size,
                              hipStream_t stream) {
    const float* x    = (const float*)d_in[0];
    const float* W_ih = (const float*)d_in[1];
    const float* W_hh = (const float*)d_in[2];
    const float* b_ih = (const float*)d_in[3];
    const float* b_hh = (const float*)d_in[4];
    const float* W_fc = (const float*)d_in[5];
    const float* b_fc = (const float*)d_in[6];
    float* out = (float*)d_out;

    const int B = in_sizes[0] / (TSEQ * IDIM);   // 8192
    lstm_fused<<<B / BPB, 256, 0, stream>>>(x, W_ih, W_hh, b_ih, b_hh, W_fc, b_fc, out);
}